// Round 1
// 74.598 us; speedup vs baseline: 1.0748x; 1.0748x over previous
//
#include <hip/hip_runtime.h>
#include <math.h>

// Problem constants (fixed by setup_inputs: B=4, N=4096, D=3)
#define NPTS   4096
#define DCH    3
#define JT     64              // j-tile: a2 refs staged in LDS per block
#define JB     (NPTS / JT)     // 64 j-blocks
#define IT     1024            // i-tile: a1 samples per block
#define IB     (NPTS / IT)     // 4 i-blocks
#define SPT    4               // i-samples per thread
#define MBLK   256
#define BATCH  4
#define G1     (BATCH * IB * JB)   // 1024 blocks -> 4/CU, 16 waves/CU
#define G2     (8 * 16)            // 128 combine blocks

typedef _Float16 h2 __attribute__((ext_vector_type(2)));
typedef _Float16 h8 __attribute__((ext_vector_type(8)));

// ---------------------------------------------------------------------------
// Direction-sharing rewrite: per batch, D[i][j] = L1(a1_i, a2_j) is the SAME
// matrix for f12 (needs col-mins over i) and f21 (needs row-mins over j).
// Old k1 computed every distance twice (once per dir). New k1 computes each
// 1024x64 tile ONCE: row-min accumulates in registers (as before), col-min
// accumulates in a 32-entry h2 register array (static indices via full
// unroll) and is block-reduced through LDS at the end. ~-35% VALU in k1.
// k2 combines 64 row-partials (f21) or 4 col-partials (f12) + GPS + sum.
// Numerics: identical fp16 op sequence per distance; min is order-invariant.
// ---------------------------------------------------------------------------
__global__ __launch_bounds__(MBLK, 4)
void k1(const float* __restrict__ a1, const float* __restrict__ a2,
        _Float16* __restrict__ rowp, _Float16* __restrict__ colp,
        float* __restrict__ out) {
    if (blockIdx.x == 0 && threadIdx.x == 0) out[0] = 0.0f;  // replaces memset

    const int jb = blockIdx.x & (JB - 1);        // 0..63
    const int ib = (blockIdx.x >> 6) & (IB - 1); // 0..3
    const int b  = blockIdx.x >> 8;              // 0..3
    const float* A1 = a1 + (size_t)b * NPTS * DCH;   // i side (f21 samples)
    const float* A2 = a2 + (size_t)b * NPTS * DCH;   // j side (f12 samples)

    __shared__ h8 lx8[JT / 8], ly8[JT / 8], lz8[JT / 8];
    __shared__ h2 lred[MBLK][33];   // col-min reduce scratch (+1 pad, 2-way free)

    {   // stage + transpose + f32->f16: threads 0..31 each pack 2 refs
        const int i = threadIdx.x;
        if (i < JT / 2) {
            const float* r = A2 + (size_t)jb * JT * DCH + 6 * i;
            h2 x, y, z;
            x.x = (_Float16)r[0]; x.y = (_Float16)r[3];
            y.x = (_Float16)r[1]; y.y = (_Float16)r[4];
            z.x = (_Float16)r[2]; z.y = (_Float16)r[5];
            ((h2*)lx8)[i] = x; ((h2*)ly8)[i] = y; ((h2*)lz8)[i] = z;
        }
    }

    const int m0 = ib * IT + threadIdx.x;
    h2 sx[SPT], sy[SPT], sz[SPT], rmin[SPT], cmin[JT / 2];
    #pragma unroll
    for (int j = 0; j < SPT; ++j) {
        const int m = m0 + j * MBLK;
        sx[j] = (h2)((_Float16)A1[3 * m + 0]);   // splat
        sy[j] = (h2)((_Float16)A1[3 * m + 1]);
        sz[j] = (h2)((_Float16)A1[3 * m + 2]);
        rmin[j] = (h2)((_Float16)65504.0f);
    }
    #pragma unroll
    for (int c = 0; c < JT / 2; ++c) cmin[c] = (h2)((_Float16)65504.0f);
    __syncthreads();

    // Full unroll (8 iters) keeps cmin indices compile-time (no scratch).
    #pragma unroll
    for (int n8 = 0; n8 < JT / 8; ++n8) {
        const h8 hx = lx8[n8];
        const h8 hy = ly8[n8];
        const h8 hz = lz8[n8];
        #define QSTEP(q)                                                     \
        {                                                                    \
            const h2 rx = __builtin_shufflevector(hx, hx, 2*(q), 2*(q)+1);   \
            const h2 ry = __builtin_shufflevector(hy, hy, 2*(q), 2*(q)+1);   \
            const h2 rz = __builtin_shufflevector(hz, hz, 2*(q), 2*(q)+1);   \
            _Pragma("unroll")                                                \
            for (int j = 0; j < SPT; ++j) {                                  \
                h2 dx = __builtin_elementwise_abs(sx[j] - rx);               \
                h2 dy = __builtin_elementwise_abs(sy[j] - ry);               \
                h2 dz = __builtin_elementwise_abs(sz[j] - rz);               \
                h2 L  = dx + dy + dz;                                        \
                rmin[j] = __builtin_elementwise_min(rmin[j], L);             \
                cmin[(n8)*4 + (q)] =                                         \
                    __builtin_elementwise_min(cmin[(n8)*4 + (q)], L);        \
            }                                                                \
        }
        QSTEP(0) QSTEP(1) QSTEP(2) QSTEP(3)
        #undef QSTEP
    }

    // f21 partial: row-min over this jb-tile -> rowp[b][jb][i]
    {
        _Float16* dst = rowp + ((size_t)(b * JB + jb)) * NPTS;
        #pragma unroll
        for (int j = 0; j < SPT; ++j) {
            const h2 d = rmin[j];
            dst[m0 + j * MBLK] = (d.x < d.y) ? d.x : d.y;
        }
    }

    // f12 partial: block-reduce cmin (256 threads x 32 h2 -> 32 h2)
    #pragma unroll
    for (int c = 0; c < JT / 2; ++c) lred[threadIdx.x][c] = cmin[c];
    __syncthreads();
    {
        const int c = threadIdx.x & 31;
        const int r = threadIdx.x >> 5;          // 8 row-groups of 32
        h2 m2 = lred[r * 32 + 0][c];
        #pragma unroll
        for (int k = 1; k < 32; ++k)
            m2 = __builtin_elementwise_min(m2, lred[r * 32 + k][c]);
        __syncthreads();
        lred[r][c] = m2;                         // 8x32 partials
    }
    __syncthreads();
    if (threadIdx.x < 32) {
        const int c = threadIdx.x;
        h2 m2 = lred[0][c];
        #pragma unroll
        for (int r = 1; r < 8; ++r)
            m2 = __builtin_elementwise_min(m2, lred[r][c]);
        // col-min partial for j = jb*64 + {2c, 2c+1}, this ib only
        ((h2*)(colp + ((size_t)(b * IB + ib)) * NPTS))[jb * 32 + c] = m2;
    }
}

__global__ __launch_bounds__(MBLK)
void k2(const _Float16* __restrict__ rowp, const _Float16* __restrict__ colp,
        const float* __restrict__ alpha_p, const float* __restrict__ beta_p,
        float* __restrict__ out, float scale) {
    const int p = blockIdx.x >> 4;        // 0..3: f12 (col), 4..7: f21 (row)
    const int g = blockIdx.x & 15;        // sample group
    const int m = g * 256 + threadIdx.x;

    const float alpha = alpha_p[0];
    const float beta  = beta_p[0];
    const float delta = powf(alpha, -1.0f / beta);

    _Float16 dh = (_Float16)65504.0f;
    if (p < 4) {                          // f12: combine 4 i-block partials
        const _Float16* src = colp + (size_t)p * IB * NPTS + m;
        #pragma unroll
        for (int k = 0; k < IB; ++k) {
            const _Float16 v = src[(size_t)k * NPTS];
            dh = (v < dh) ? v : dh;
        }
    } else {                              // f21: combine 64 j-block partials
        const _Float16* src = rowp + (size_t)(p - 4) * JB * NPTS + m;
        #pragma unroll
        for (int k = 0; k < JB; ++k) {
            const _Float16 v = src[(size_t)k * NPTS];
            dh = (v < dh) ? v : dh;
        }
    }
    const float dmin = (float)dh;

    const float s = alpha * exp2f(beta * log2f(dmin)) + delta;   // dmin > 0
    float acc = -s * expf(-s);

    for (int off = 32; off > 0; off >>= 1)
        acc += __shfl_down(acc, off, 64);

    __shared__ float red[4];
    if ((threadIdx.x & 63) == 0) red[threadIdx.x >> 6] = acc;
    __syncthreads();
    if (threadIdx.x == 0)
        atomicAdd(out, (red[0] + red[1] + red[2] + red[3]) * scale);
}

extern "C" void kernel_launch(void* const* d_in, const int* in_sizes, int n_in,
                              void* d_out, int out_size, void* d_ws, size_t ws_size,
                              hipStream_t stream) {
    const float* a1    = (const float*)d_in[0];
    const float* a2    = (const float*)d_in[1];
    const float* alpha = (const float*)d_in[2];
    const float* beta  = (const float*)d_in[3];
    float* out = (float*)d_out;

    _Float16* rowp = (_Float16*)d_ws;                       // 4*64*4096 fp16 = 2 MiB
    _Float16* colp = rowp + (size_t)BATCH * JB * NPTS;      // 4*4*4096 fp16 = 128 KiB

    const int B = in_sizes[0] / (NPTS * DCH);       // 4
    const float scale = 100.0f * 0.5f / (float)B;   // 12.5

    k1<<<G1, MBLK, 0, stream>>>(a1, a2, rowp, colp, out);
    k2<<<G2, MBLK, 0, stream>>>(rowp, colp, alpha, beta, out, scale);
}